// Round 4
// baseline (3583.620 us; speedup 1.0000x reference)
//
#include <hip/hip_runtime.h>
#include <stdint.h>
#include <stddef.h>

typedef unsigned short u16;
using f16    = _Float16;
using f16x2  = __attribute__((ext_vector_type(2))) _Float16;
using f16x8  = __attribute__((ext_vector_type(8))) _Float16;
using bf16x8 = __attribute__((ext_vector_type(8))) short;
using f32x4  = __attribute__((ext_vector_type(4))) float;

__device__ __forceinline__ short f2bf(float f) {
  uint32_t u = __builtin_bit_cast(uint32_t, f);
  u += 0x7FFFu + ((u >> 16) & 1u);   // RNE
  return (short)(u >> 16);
}
__device__ __forceinline__ u16 f2h(float f) {
  return __builtin_bit_cast(u16, (f16)f);
}

// async global->LDS, 16B per lane; LDS dest must be wave-contiguous (m97/m104)
typedef const __attribute__((address_space(1))) void* gas_t;
typedef __attribute__((address_space(3))) void* las_t;
__device__ __forceinline__ void async16(const void* g, void* l) {
  __builtin_amdgcn_global_load_lds((gas_t)g, (las_t)l, 16, 0, 0);
}

__device__ __forceinline__ float wred(float v) {
#pragma unroll
  for (int o = 32; o; o >>= 1) v += __shfl_xor(v, o, 64);
  return v;
}
__device__ __forceinline__ float wredmax(float v) {
#pragma unroll
  for (int o = 32; o; o >>= 1) v = fmaxf(v, __shfl_xor(v, o, 64));
  return v;
}

// sum of 8 f16 lanes into fp32 acc via 4x v_dot2_f32_f16
__device__ __forceinline__ float dot8(f16x8 v, float acc) {
  union { f16x8 v8; f16x2 v2[4]; } u;
  u.v8 = v;
  const f16x2 one2 = {(f16)1, (f16)1};
  acc = __builtin_amdgcn_fdot2(u.v2[0], one2, acc, false);
  acc = __builtin_amdgcn_fdot2(u.v2[1], one2, acc, false);
  acc = __builtin_amdgcn_fdot2(u.v2[2], one2, acc, false);
  acc = __builtin_amdgcn_fdot2(u.v2[3], one2, acc, false);
  return acc;
}
// horizontal max of f16x8 -> float
__device__ __forceinline__ float hmax8(f16x8 v) {
  union { f16x8 v8; f16x2 v2[4]; } u;
  u.v8 = v;
  f16x2 a = __builtin_elementwise_max(u.v2[0], u.v2[1]);
  f16x2 b = __builtin_elementwise_max(u.v2[2], u.v2[3]);
  f16x2 c = __builtin_elementwise_max(a, b);
  return fmaxf((float)c[0], (float)c[1]);
}

// ---------------------------------------------------------------- convert ---
struct ConvArgs {
  const float* src[8];
  u16* dst[8];
  int start4[9];   // exclusive prefix in float4 units
};

__global__ __launch_bounds__(256) void convert_all(ConvArgs a) {
  int idx = blockIdx.x * 256 + threadIdx.x;
  if (idx >= a.start4[8]) return;
  int s = 0;
#pragma unroll
  for (int i = 1; i < 8; ++i) s += (idx >= a.start4[i]) ? 1 : 0;
  int off = idx - a.start4[s];
  const float4* sp = (const float4*)a.src[s];
  float4 v = sp[off];
  ushort4 o;
  o.x = (u16)f2bf(v.x); o.y = (u16)f2bf(v.y);
  o.z = (u16)f2bf(v.z); o.w = (u16)f2bf(v.w);
  *(ushort4*)(a.dst[s] + (size_t)off * 4) = o;
}

__global__ __launch_bounds__(256) void zero_u16(u16* p, int n) {
  int i = blockIdx.x * 256 + threadIdx.x;
  if (i < n) p[i] = 0;
}

// ------------------------------------------------------------------- GEMM ---
// C[M,N] = A[M,K1] @ B[N,K1]^T (+ A2@B2^T if DUAL) + bias, optional relu.
// bf16 inputs, m97 structure, global_load_lds width-16 staging.
// TM in {64,128}: tile TM x 128. M % TM == 0; N padded/guarded.
// BIAS: 0 none, 1 per-col, 2 per-row. OUTT: 0 f32, 1 bf16, 2 f16.
template<int BIAS, bool RELU, int OUTT, bool DUAL, int TM>
__global__ __launch_bounds__(256) void gemm_nt(
    const u16* __restrict__ A, int lda,
    const u16* __restrict__ B, int ldb,
    const u16* __restrict__ A2, int lda2,
    const u16* __restrict__ B2, int ldb2,
    int K1, int K2,
    const float* __restrict__ bias,
    void* __restrict__ C, int ldc, int N)
{
  constexpr int MI = (TM == 128) ? 4 : 2;   // 16-row m-frags per wave
  __shared__ u16 As[TM * 32];
  __shared__ u16 Bs[128 * 32];

  const int tid  = threadIdx.x;
  const int m0   = blockIdx.y * TM;
  const int n0   = blockIdx.x * 128;
  const int wave = tid >> 6, lane = tid & 63;
  const int lrow = lane & 15, quad = lane >> 4;
  const int wm   = (TM == 128) ? (wave & 1) * 64 : (wave >> 1) * 32;
  const int wn   = (TM == 128) ? (wave >> 1) * 64 : (wave & 1) * 64;

  f32x4 zero = {0.f, 0.f, 0.f, 0.f};
  f32x4 acc[MI][4];
#pragma unroll
  for (int i = 0; i < MI; ++i)
#pragma unroll
    for (int j = 0; j < 4; ++j) acc[i][j] = zero;

  const int KK = DUAL ? (K1 + K2) : K1;
  for (int k0 = 0; k0 < KK; k0 += 32) {
    const u16* Ap; const u16* Bp; int la, lb, kk;
    if (!DUAL || k0 < K1) { Ap = A;  Bp = B;  la = lda;  lb = ldb;  kk = k0; }
    else                  { Ap = A2; Bp = B2; la = lda2; lb = ldb2; kk = k0 - K1; }

#pragma unroll
    for (int i = 0; i < TM / 64; ++i) {       // A: TM*4 chunks of 16B
      int idx = i * 256 + tid;
      int row = idx >> 2, c8 = (idx & 3) * 8;
      async16(Ap + (size_t)(m0 + row) * la + kk + c8, &As[idx * 8]);
    }
#pragma unroll
    for (int i = 0; i < 2; ++i) {             // B: 512 chunks of 16B
      int idx = i * 256 + tid;
      int row = idx >> 2, c8 = (idx & 3) * 8;
      async16(Bp + (size_t)(n0 + row) * lb + kk + c8, &Bs[idx * 8]);
    }
    __syncthreads();

    bf16x8 af[MI], bfr[4];
#pragma unroll
    for (int i = 0; i < MI; ++i)
      af[i] = *(const bf16x8*)(&As[(wm + i * 16 + lrow) * 32 + quad * 8]);
#pragma unroll
    for (int j = 0; j < 4; ++j)
      bfr[j] = *(const bf16x8*)(&Bs[(wn + j * 16 + lrow) * 32 + quad * 8]);
#pragma unroll
    for (int i = 0; i < MI; ++i)
#pragma unroll
      for (int j = 0; j < 4; ++j)
        acc[i][j] = __builtin_amdgcn_mfma_f32_16x16x32_bf16(af[i], bfr[j], acc[i][j], 0, 0, 0);
    __syncthreads();
  }

  // epilogue: C layout col=lane&15, row=quad*4+r
#pragma unroll
  for (int i = 0; i < MI; ++i) {
#pragma unroll
    for (int j = 0; j < 4; ++j) {
      int gn = n0 + wn + j * 16 + lrow;
      if (gn >= N) continue;
      float bc = (BIAS == 1) ? bias[gn] : 0.0f;
#pragma unroll
      for (int r = 0; r < 4; ++r) {
        int gm = m0 + wm + i * 16 + quad * 4 + r;
        float v = acc[i][j][r] + bc;
        if (BIAS == 2) v += bias[gm];
        if (RELU) v = fmaxf(v, 0.0f);
        if (OUTT == 1)      ((u16*)C)[(size_t)gm * ldc + gn] = (u16)f2bf(v);
        else if (OUTT == 2) ((u16*)C)[(size_t)gm * ldc + gn] = f2h(v);
        else                ((float*)C)[(size_t)gm * ldc + gn] = v;
      }
    }
  }
}

// ------------------------------------------------- fused attention+sparsemax
// One block per (head, 16-query tile). 512 threads = 8 waves.
// Key-chunked LDS (4 x 1024) -> 41 KB -> 2 blocks/CU. Full 4096-key row
// stays register-resident (z0/z1). Newton from tau0 = rowmax-1.
__global__ __launch_bounds__(512, 4) void attn_sparsemax(
    const f16* __restrict__ Q,    // [2048][1024] f16
    const f16* __restrict__ Km,   // [4096][1024] f16
    const f16* __restrict__ Vt,   // [1024][4096] f16 (V transposed)
    u16* __restrict__ AO)         // [2048][1024] bf16
{
  constexpr int CROW = 1024 + 8;          // +8 pad: 4-bank row shift
  __shared__ f16 Sc[16 * CROW];           // 33 KB (one 1024-key chunk)
  __shared__ float Ored[2][4][256];       // cross-wave O reduction, 8 KB

  const int id    = blockIdx.x;
  const int head  = (id & 7) * 2 + ((id >> 3) >> 7);  // 2 heads/XCD
  const int qblk  = (id >> 3) & 127;
  const int qbase = qblk * 16;
  const int tid   = threadIdx.x;
  const int wave  = tid >> 6, lane = tid & 63;
  const int lrow  = lane & 15, quad = lane >> 4;

  // Q fragments (A-operand: m=lane&15, k=quad*8+j)
  const f16* qp = Q + (size_t)(qbase + lrow) * 1024 + head * 64 + quad * 8;
  f16x8 qf0 = *(const f16x8*)qp;
  f16x8 qf1 = *(const f16x8*)(qp + 32);

  const int row0 = wave * 2, row1 = row0 + 1;
  f16x8 z0[8], z1[8];                     // full 4096-key rows, registers

  // ---- phase A: scores per 1024-key chunk; gather own rows to regs ----------
  const float scale = 1.0f / 32.0f;
#pragma unroll 1
  for (int ch = 0; ch < 4; ++ch) {
#pragma unroll
    for (int kt = 0; kt < 8; ++kt) {
      int key0 = ch * 1024 + wave * 128 + kt * 16;
      const f16* kp = Km + (size_t)(key0 + lrow) * 1024 + head * 64 + quad * 8;
      f16x8 kf0 = *(const f16x8*)kp;
      f16x8 kf1 = *(const f16x8*)(kp + 32);
      f32x4 sc = {0.f, 0.f, 0.f, 0.f};
      sc = __builtin_amdgcn_mfma_f32_16x16x32_f16(qf0, kf0, sc, 0, 0, 0);
      sc = __builtin_amdgcn_mfma_f32_16x16x32_f16(qf1, kf1, sc, 0, 0, 0);
      int lk = wave * 128 + kt * 16 + lrow;
#pragma unroll
      for (int r = 0; r < 4; ++r)
        Sc[(quad * 4 + r) * CROW + lk] = (f16)(sc[r] * scale);
    }
    __syncthreads();
    z0[ch * 2 + 0] = *(const f16x8*)(&Sc[row0 * CROW + lane * 8]);
    z0[ch * 2 + 1] = *(const f16x8*)(&Sc[row0 * CROW + 512 + lane * 8]);
    z1[ch * 2 + 0] = *(const f16x8*)(&Sc[row1 * CROW + lane * 8]);
    z1[ch * 2 + 1] = *(const f16x8*)(&Sc[row1 * CROW + 512 + lane * 8]);
    __syncthreads();
  }

  // ---- phase B: Newton for tau, start at rowmax - 1 -------------------------
  const f16 bg = (f16)65504.0f;
  const f16x8 big8  = {bg, bg, bg, bg, bg, bg, bg, bg};
  const f16x8 one8  = {(f16)1, (f16)1, (f16)1, (f16)1, (f16)1, (f16)1, (f16)1, (f16)1};
  const f16x8 zero8 = {(f16)0, (f16)0, (f16)0, (f16)0, (f16)0, (f16)0, (f16)0, (f16)0};

  f16x8 mx0 = z0[0], mx1 = z1[0];
#pragma unroll
  for (int t = 1; t < 8; ++t) {
    mx0 = __builtin_elementwise_max(mx0, z0[t]);
    mx1 = __builtin_elementwise_max(mx1, z1[t]);
  }
  float tau0 = wredmax(hmax8(mx0)) - 1.0f;
  float tau1 = wredmax(hmax8(mx1)) - 1.0f;

  bool c0 = false, c1 = false;
#pragma unroll 1
  for (int it = 0; it < 16; ++it) {
    f16 t0 = (f16)tau0, t1 = (f16)tau1;
    f16x8 t08 = {t0, t0, t0, t0, t0, t0, t0, t0};
    f16x8 t18 = {t1, t1, t1, t1, t1, t1, t1, t1};
    float lsA0 = 0.f, lsB0 = 0.f, lcA0 = 0.f, lcB0 = 0.f;
    float lsA1 = 0.f, lsB1 = 0.f, lcA1 = 0.f, lcB1 = 0.f;
#pragma unroll
    for (int t = 0; t < 8; t += 2) {
      f16x8 ma = __builtin_elementwise_max(z0[t] - t08, zero8);
      f16x8 mb = __builtin_elementwise_max(z0[t + 1] - t08, zero8);
      f16x8 mc = __builtin_elementwise_max(z1[t] - t18, zero8);
      f16x8 md = __builtin_elementwise_max(z1[t + 1] - t18, zero8);
      lsA0 = dot8(ma, lsA0);
      lsB0 = dot8(mb, lsB0);
      lsA1 = dot8(mc, lsA1);
      lsB1 = dot8(md, lsB1);
      lcA0 = dot8(__builtin_elementwise_min(ma * big8, one8), lcA0);
      lcB0 = dot8(__builtin_elementwise_min(mb * big8, one8), lcB0);
      lcA1 = dot8(__builtin_elementwise_min(mc * big8, one8), lcA1);
      lcB1 = dot8(__builtin_elementwise_min(md * big8, one8), lcB1);
    }
    float ls0 = wred(lsA0 + lsB0), lc0 = wred(lcA0 + lcB0);
    float ls1 = wred(lsA1 + lsB1), lc1 = wred(lcA1 + lcB1);
    if (!c0) {
      if (lc0 < 0.5f) c0 = true;
      else {
        float n0 = tau0 + (ls0 - 1.0f) / lc0;
        if (n0 <= tau0) c0 = true; else tau0 = n0;
      }
    }
    if (!c1) {
      if (lc1 < 0.5f) c1 = true;
      else {
        float n1 = tau1 + (ls1 - 1.0f) / lc1;
        if (n1 <= tau1) c1 = true; else tau1 = n1;
      }
    }
    if (c0 && c1) break;
  }

  // ---- phase C: per chunk, write P to LDS and accumulate P@V ----------------
  const int dhg = wave & 3, kh = wave >> 2;
  f32x4 oacc = {0.f, 0.f, 0.f, 0.f};
  const f16* vbase0 = Vt + (size_t)(head * 64 + dhg * 16 + lrow) * 4096 + kh * 512 + quad * 8;
  const f16* pbase  = &Sc[lrow * CROW + kh * 512 + quad * 8];
  f16 t0 = (f16)tau0, t1 = (f16)tau1;
  f16x8 t08 = {t0, t0, t0, t0, t0, t0, t0, t0};
  f16x8 t18 = {t1, t1, t1, t1, t1, t1, t1, t1};

#pragma unroll 1
  for (int ch = 0; ch < 4; ++ch) {
    *(f16x8*)(&Sc[row0 * CROW + lane * 8])       = __builtin_elementwise_max(z0[2 * ch] - t08, zero8);
    *(f16x8*)(&Sc[row0 * CROW + 512 + lane * 8]) = __builtin_elementwise_max(z0[2 * ch + 1] - t08, zero8);
    *(f16x8*)(&Sc[row1 * CROW + lane * 8])       = __builtin_elementwise_max(z1[2 * ch] - t18, zero8);
    *(f16x8*)(&Sc[row1 * CROW + 512 + lane * 8]) = __builtin_elementwise_max(z1[2 * ch + 1] - t18, zero8);
    __syncthreads();
    const f16* vrow = vbase0 + ch * 1024;
#pragma unroll
    for (int kt = 0; kt < 16; ++kt) {
      f16x8 pf = *(const f16x8*)(pbase + kt * 32);
      f16x8 vf = *(const f16x8*)(vrow + kt * 32);
      oacc = __builtin_amdgcn_mfma_f32_16x16x32_f16(pf, vf, oacc, 0, 0, 0);
    }
    __syncthreads();
  }

  float* orp = &Ored[kh][dhg][0];
#pragma unroll
  for (int r = 0; r < 4; ++r) orp[(quad * 4 + r) * 16 + lrow] = oacc[r];
  __syncthreads();
  if (kh == 0) {
    const float* other = &Ored[1][dhg][0];
#pragma unroll
    for (int r = 0; r < 4; ++r) {
      float v = oacc[r] + other[(quad * 4 + r) * 16 + lrow];
      AO[(size_t)(qbase + quad * 4 + r) * 1024 + head * 64 + dhg * 16 + lrow] = (u16)f2bf(v);
    }
  }
}

// ---------------------------------------------------------------- launcher --
extern "C" void kernel_launch(void* const* d_in, const int* in_sizes, int n_in,
                              void* d_out, int out_size, void* d_ws, size_t ws_size,
                              hipStream_t stream) {
  const float* enc = (const float*)d_in[0];
  const float* mem = (const float*)d_in[1];
  const float* Wq  = (const float*)d_in[2];
  const float* bq  = (const float*)d_in[3];
  const float* Wk  = (const float*)d_in[4];
  const float* bk  = (const float*)d_in[5];
  const float* Wv  = (const float*)d_in[6];
  const float* bv  = (const float*)d_in[7];
  const float* Wo  = (const float*)d_in[8];
  const float* bo  = (const float*)d_in[9];
  const float* W1  = (const float*)d_in[10];
  const float* b1  = (const float*)d_in[11];
  const float* W2  = (const float*)d_in[12];
  const float* b2  = (const float*)d_in[13];

  char* ws = (char*)d_ws;
  const size_t MB = 1024 * 1024;
  u16* enc_bf = (u16*)(ws + 0 * MB);   // 2048x1024 bf16
  u16* mem_bf = (u16*)(ws + 4 * MB);   // 4096x1024 bf16
  u16* Wq_bf  = (u16*)(ws + 12 * MB);
  u16* Wk_bf  = (u16*)(ws + 14 * MB);
  u16* Wv_bf  = (u16*)(ws + 16 * MB);
  u16* Wo_bf  = (u16*)(ws + 18 * MB);
  u16* W1_bf  = (u16*)(ws + 20 * MB);  // 4096x2048
  u16* W2_bf  = (u16*)(ws + 36 * MB);  // 1024x4096 (padded from 1000)
  u16* Qb     = (u16*)(ws + 46 * MB);  // 2048x1024 f16
  u16* Kb     = (u16*)(ws + 50 * MB);  // 4096x1024 f16
  u16* Vtb    = (u16*)(ws + 58 * MB);  // 1024x4096 f16 (V^T)
  u16* AO     = (u16*)(ws + 66 * MB);  // 2048x1024 bf16
  u16* OUT    = (u16*)(ws + 70 * MB);  // 2048x1024 bf16
  u16* Hh     = (u16*)(ws + 74 * MB);  // 2048x4096 bf16

  ConvArgs ca;
  const float* srcs[8] = {enc, mem, Wq, Wk, Wv, Wo, W1, W2};
  u16* dsts[8] = {enc_bf, mem_bf, Wq_bf, Wk_bf, Wv_bf, Wo_bf, W1_bf, W2_bf};
  int sizes[8] = {2048 * 1024, 4096 * 1024, 1024 * 1024, 1024 * 1024,
                  1024 * 1024, 1024 * 1024, 4096 * 2048, 1000 * 4096};
  int start = 0;
  for (int i = 0; i < 8; ++i) {
    ca.src[i] = srcs[i]; ca.dst[i] = dsts[i];
    ca.start4[i] = start; start += sizes[i] / 4;
  }
  ca.start4[8] = start;
  convert_all<<<(start + 255) / 256, 256, 0, stream>>>(ca);
  zero_u16<<<(24 * 4096 + 255) / 256, 256, 0, stream>>>(W2_bf + 1000 * 4096, 24 * 4096);

  // Q = enc @ Wq^T + bq  (f16 out)  [2048,1024]  TM=64 -> 256 blocks
  gemm_nt<1, false, 2, false, 64><<<dim3(8, 32), 256, 0, stream>>>(
      enc_bf, 1024, Wq_bf, 1024, nullptr, 0, nullptr, 0, 1024, 0, bq, Qb, 1024, 1024);
  // K = mem @ Wk^T + bk  (f16 out)  [4096,1024]  TM=64 -> 512 blocks
  gemm_nt<1, false, 2, false, 64><<<dim3(8, 64), 256, 0, stream>>>(
      mem_bf, 1024, Wk_bf, 1024, nullptr, 0, nullptr, 0, 1024, 0, bk, Kb, 1024, 1024);
  // V^T = Wv @ mem^T + bv (row bias, f16 out)  [1024,4096]  TM=64 -> 512 blocks
  gemm_nt<2, false, 2, false, 64><<<dim3(32, 16), 256, 0, stream>>>(
      Wv_bf, 1024, mem_bf, 1024, nullptr, 0, nullptr, 0, 1024, 0, bv, Vtb, 4096, 4096);
  // attention + sparsemax
  attn_sparsemax<<<2048, 512, 0, stream>>>((const f16*)Qb, (const f16*)Kb, (const f16*)Vtb, AO);
  // OUT = AO @ Wo^T + bo (bf16 out)  [2048,1024]  TM=64 -> 256 blocks
  gemm_nt<1, false, 1, false, 64><<<dim3(8, 32), 256, 0, stream>>>(
      AO, 1024, Wo_bf, 1024, nullptr, 0, nullptr, 0, 1024, 0, bo, OUT, 1024, 1024);
  // H = relu(enc@W1a^T + OUT@W1b^T + b1)  [2048,4096]  TM=128 -> 512 blocks
  gemm_nt<1, true, 1, true, 128><<<dim3(32, 16), 256, 0, stream>>>(
      enc_bf, 1024, W1_bf, 2048, OUT, 1024, W1_bf + 1024, 2048, 1024, 1024, b1, Hh, 4096, 4096);
  // out = H @ W2^T + b2 (fp32 out, N=1000)  [2048,1000]  TM=64 -> 256 blocks
  gemm_nt<1, false, 0, false, 64><<<dim3(8, 32), 256, 0, stream>>>(
      Hh, 4096, W2_bf, 4096, nullptr, 0, nullptr, 0, 4096, 0, b2, d_out, 1000, 1000);
}

// Round 5
// 792.418 us; speedup vs baseline: 4.5224x; 4.5224x over previous
//
#include <hip/hip_runtime.h>
#include <stdint.h>
#include <stddef.h>

typedef unsigned short u16;
using f16    = _Float16;
using f16x2  = __attribute__((ext_vector_type(2))) _Float16;
using f16x8  = __attribute__((ext_vector_type(8))) _Float16;
using bf16x8 = __attribute__((ext_vector_type(8))) short;
using f32x4  = __attribute__((ext_vector_type(4))) float;

__device__ __forceinline__ short f2bf(float f) {
  uint32_t u = __builtin_bit_cast(uint32_t, f);
  u += 0x7FFFu + ((u >> 16) & 1u);   // RNE
  return (short)(u >> 16);
}
__device__ __forceinline__ u16 f2h(float f) {
  return __builtin_bit_cast(u16, (f16)f);
}

// async global->LDS, 16B per lane; LDS dest must be wave-contiguous (m97/m104)
typedef const __attribute__((address_space(1))) void* gas_t;
typedef __attribute__((address_space(3))) void* las_t;
__device__ __forceinline__ void async16(const void* g, void* l) {
  __builtin_amdgcn_global_load_lds((gas_t)g, (las_t)l, 16, 0, 0);
}

__device__ __forceinline__ float wred(float v) {
#pragma unroll
  for (int o = 32; o; o >>= 1) v += __shfl_xor(v, o, 64);
  return v;
}

// sum of 8 f16 lanes into fp32 acc via 4x v_dot2_f32_f16
__device__ __forceinline__ float dot8(f16x8 v, float acc) {
  union { f16x8 v8; f16x2 v2[4]; } u;
  u.v8 = v;
  const f16x2 one2 = {(f16)1, (f16)1};
  acc = __builtin_amdgcn_fdot2(u.v2[0], one2, acc, false);
  acc = __builtin_amdgcn_fdot2(u.v2[1], one2, acc, false);
  acc = __builtin_amdgcn_fdot2(u.v2[2], one2, acc, false);
  acc = __builtin_amdgcn_fdot2(u.v2[3], one2, acc, false);
  return acc;
}

// ---------------------------------------------------------------- convert ---
struct ConvArgs {
  const float* src[8];
  u16* dst[8];
  int start4[9];   // exclusive prefix in float4 units
};

__global__ __launch_bounds__(256) void convert_all(ConvArgs a) {
  int idx = blockIdx.x * 256 + threadIdx.x;
  if (idx >= a.start4[8]) return;
  int s = 0;
#pragma unroll
  for (int i = 1; i < 8; ++i) s += (idx >= a.start4[i]) ? 1 : 0;
  int off = idx - a.start4[s];
  const float4* sp = (const float4*)a.src[s];
  float4 v = sp[off];
  ushort4 o;
  o.x = (u16)f2bf(v.x); o.y = (u16)f2bf(v.y);
  o.z = (u16)f2bf(v.z); o.w = (u16)f2bf(v.w);
  *(ushort4*)(a.dst[s] + (size_t)off * 4) = o;
}

__global__ __launch_bounds__(256) void zero_u16(u16* p, int n) {
  int i = blockIdx.x * 256 + threadIdx.x;
  if (i < n) p[i] = 0;
}

// ------------------------------------------------------------------- GEMM ---
// C[M,N] = A[M,K1] @ B[N,K1]^T (+ A2@B2^T if DUAL) + bias, optional relu.
// bf16 inputs, m97 structure, global_load_lds width-16 staging.
// TM in {64,128}: tile TM x 128. M % TM == 0; N padded/guarded.
// BIAS: 0 none, 1 per-col, 2 per-row. OUTT: 0 f32, 1 bf16, 2 f16.
template<int BIAS, bool RELU, int OUTT, bool DUAL, int TM>
__global__ __launch_bounds__(256) void gemm_nt(
    const u16* __restrict__ A, int lda,
    const u16* __restrict__ B, int ldb,
    const u16* __restrict__ A2, int lda2,
    const u16* __restrict__ B2, int ldb2,
    int K1, int K2,
    const float* __restrict__ bias,
    void* __restrict__ C, int ldc, int N)
{
  constexpr int MI = (TM == 128) ? 4 : 2;   // 16-row m-frags per wave
  __shared__ u16 As[TM * 32];
  __shared__ u16 Bs[128 * 32];

  const int tid  = threadIdx.x;
  const int m0   = blockIdx.y * TM;
  const int n0   = blockIdx.x * 128;
  const int wave = tid >> 6, lane = tid & 63;
  const int lrow = lane & 15, quad = lane >> 4;
  const int wm   = (TM == 128) ? (wave & 1) * 64 : (wave >> 1) * 32;
  const int wn   = (TM == 128) ? (wave >> 1) * 64 : (wave & 1) * 64;

  f32x4 zero = {0.f, 0.f, 0.f, 0.f};
  f32x4 acc[MI][4];
#pragma unroll
  for (int i = 0; i < MI; ++i)
#pragma unroll
    for (int j = 0; j < 4; ++j) acc[i][j] = zero;

  const int KK = DUAL ? (K1 + K2) : K1;
  for (int k0 = 0; k0 < KK; k0 += 32) {
    const u16* Ap; const u16* Bp; int la, lb, kk;
    if (!DUAL || k0 < K1) { Ap = A;  Bp = B;  la = lda;  lb = ldb;  kk = k0; }
    else                  { Ap = A2; Bp = B2; la = lda2; lb = ldb2; kk = k0 - K1; }

#pragma unroll
    for (int i = 0; i < TM / 64; ++i) {       // A: TM*4 chunks of 16B
      int idx = i * 256 + tid;
      int row = idx >> 2, c8 = (idx & 3) * 8;
      async16(Ap + (size_t)(m0 + row) * la + kk + c8, &As[idx * 8]);
    }
#pragma unroll
    for (int i = 0; i < 2; ++i) {             // B: 512 chunks of 16B
      int idx = i * 256 + tid;
      int row = idx >> 2, c8 = (idx & 3) * 8;
      async16(Bp + (size_t)(n0 + row) * lb + kk + c8, &Bs[idx * 8]);
    }
    __syncthreads();

    bf16x8 af[MI], bfr[4];
#pragma unroll
    for (int i = 0; i < MI; ++i)
      af[i] = *(const bf16x8*)(&As[(wm + i * 16 + lrow) * 32 + quad * 8]);
#pragma unroll
    for (int j = 0; j < 4; ++j)
      bfr[j] = *(const bf16x8*)(&Bs[(wn + j * 16 + lrow) * 32 + quad * 8]);
#pragma unroll
    for (int i = 0; i < MI; ++i)
#pragma unroll
      for (int j = 0; j < 4; ++j)
        acc[i][j] = __builtin_amdgcn_mfma_f32_16x16x32_bf16(af[i], bfr[j], acc[i][j], 0, 0, 0);
    __syncthreads();
  }

  // epilogue: C layout col=lane&15, row=quad*4+r
#pragma unroll
  for (int i = 0; i < MI; ++i) {
#pragma unroll
    for (int j = 0; j < 4; ++j) {
      int gn = n0 + wn + j * 16 + lrow;
      if (gn >= N) continue;
      float bc = (BIAS == 1) ? bias[gn] : 0.0f;
#pragma unroll
      for (int r = 0; r < 4; ++r) {
        int gm = m0 + wm + i * 16 + quad * 4 + r;
        float v = acc[i][j][r] + bc;
        if (BIAS == 2) v += bias[gm];
        if (RELU) v = fmaxf(v, 0.0f);
        if (OUTT == 1)      ((u16*)C)[(size_t)gm * ldc + gn] = (u16)f2bf(v);
        else if (OUTT == 2) ((u16*)C)[(size_t)gm * ldc + gn] = f2h(v);
        else                ((float*)C)[(size_t)gm * ldc + gn] = v;
      }
    }
  }
}

// ------------------------------------------------- fused attention+sparsemax
// One block per (head, 16-query tile). 1024 threads = 16 waves (4 waves/SIMD
// at 1 block/CU -- LDS 147.7 KB). Full S[16][4104] f16 in LDS; each wave owns
// ONE row: Newton in registers (z read once from LDS, P written back).
__global__ __launch_bounds__(1024) void attn_sparsemax(
    const f16* __restrict__ Q,    // [2048][1024] f16
    const f16* __restrict__ Km,   // [4096][1024] f16
    const f16* __restrict__ Vt,   // [1024][4096] f16 (V transposed)
    u16* __restrict__ AO)         // [2048][1024] bf16
{
  constexpr int SROW = 4096 + 8;          // +8 pad
  __shared__ f16 S[16 * SROW];            // 131,328 B
  __shared__ float Ored[4][4][256];       // 4 ksegs x 4 dhg x 16x16 tile, 16 KB

  const int id    = blockIdx.x;
  const int head  = (id & 7) * 2 + ((id >> 3) >> 7);  // 2 heads/XCD
  const int qblk  = (id >> 3) & 127;
  const int qbase = qblk * 16;
  const int tid   = threadIdx.x;
  const int wave  = tid >> 6, lane = tid & 63;
  const int lrow  = lane & 15, quad = lane >> 4;

  // Q fragments (A-operand: m=lane&15, k=quad*8+j)
  const f16* qp = Q + (size_t)(qbase + lrow) * 1024 + head * 64 + quad * 8;
  f16x8 qf0 = *(const f16x8*)qp;
  f16x8 qf1 = *(const f16x8*)(qp + 32);

  // ---- phase A: scores; wave w owns keys [w*256, w*256+256) -----------------
  const float scale = 1.0f / 32.0f;
#pragma unroll 2
  for (int kt = 0; kt < 16; ++kt) {
    int key0 = wave * 256 + kt * 16;
    const f16* kp = Km + (size_t)(key0 + lrow) * 1024 + head * 64 + quad * 8;
    f16x8 kf0 = *(const f16x8*)kp;
    f16x8 kf1 = *(const f16x8*)(kp + 32);
    f32x4 sc = {0.f, 0.f, 0.f, 0.f};
    sc = __builtin_amdgcn_mfma_f32_16x16x32_f16(qf0, kf0, sc, 0, 0, 0);
    sc = __builtin_amdgcn_mfma_f32_16x16x32_f16(qf1, kf1, sc, 0, 0, 0);
#pragma unroll
    for (int r = 0; r < 4; ++r)
      S[(quad * 4 + r) * SROW + key0 + lrow] = (f16)(sc[r] * scale);
  }
  __syncthreads();

  // ---- phase B: Newton for tau; wave w owns row w (z in regs, phase-local) --
  const f16 bg = (f16)65504.0f;
  const f16x8 big8  = {bg, bg, bg, bg, bg, bg, bg, bg};
  const f16x8 one8  = {(f16)1, (f16)1, (f16)1, (f16)1, (f16)1, (f16)1, (f16)1, (f16)1};
  const f16x8 zero8 = {(f16)0, (f16)0, (f16)0, (f16)0, (f16)0, (f16)0, (f16)0, (f16)0};

  {
    const int row = wave;
    f16x8 z[8];
    float sA = 0.f, sB = 0.f;
#pragma unroll
    for (int t = 0; t < 8; t += 2) {
      z[t]     = *(const f16x8*)(&S[row * SROW + t * 512 + lane * 8]);
      z[t + 1] = *(const f16x8*)(&S[row * SROW + (t + 1) * 512 + lane * 8]);
      sA = dot8(z[t], sA);
      sB = dot8(z[t + 1], sB);
    }
    float tau = (wred(sA + sB) - 1.0f) * (1.0f / 4096.0f);

#pragma unroll 1
    for (int it = 0; it < 14; ++it) {
      f16 tq = (f16)tau;
      f16x8 t8 = {tq, tq, tq, tq, tq, tq, tq, tq};
      float lsA = 0.f, lsB = 0.f, lcA = 0.f, lcB = 0.f;
#pragma unroll
      for (int t = 0; t < 8; t += 2) {
        f16x8 ma = __builtin_elementwise_max(z[t] - t8, zero8);
        f16x8 mb = __builtin_elementwise_max(z[t + 1] - t8, zero8);
        lsA = dot8(ma, lsA);
        lsB = dot8(mb, lsB);
        lcA = dot8(__builtin_elementwise_min(ma * big8, one8), lcA);
        lcB = dot8(__builtin_elementwise_min(mb * big8, one8), lcB);
      }
      float ls = wred(lsA + lsB), lc = wred(lcA + lcB);
      if (lc < 0.5f) break;
      float nt = tau + (ls - 1.0f) / lc;
      if (nt <= tau) break;              // monotone climb converged
      tau = nt;
    }

    // write P = max(z - tau, 0) back to S
    f16 tq = (f16)tau;
    f16x8 t8 = {tq, tq, tq, tq, tq, tq, tq, tq};
#pragma unroll
    for (int t = 0; t < 8; ++t)
      *(f16x8*)(&S[row * SROW + t * 512 + lane * 8]) =
          __builtin_elementwise_max(z[t] - t8, zero8);
  }
  __syncthreads();

  // ---- phase C: O = P @ V; wave = (dhg, kseg), kseg covers 1024 keys --------
  const int dhg = wave & 3, kseg = wave >> 2;
  f32x4 oacc = {0.f, 0.f, 0.f, 0.f};
  const f16* vrow = Vt + (size_t)(head * 64 + dhg * 16 + lrow) * 4096 + kseg * 1024 + quad * 8;
  const f16* prow = &S[lrow * SROW + kseg * 1024 + quad * 8];
#pragma unroll 4
  for (int kt = 0; kt < 32; ++kt) {
    f16x8 pf = *(const f16x8*)(prow + kt * 32);
    f16x8 vf = *(const f16x8*)(vrow + kt * 32);
    oacc = __builtin_amdgcn_mfma_f32_16x16x32_f16(pf, vf, oacc, 0, 0, 0);
  }
  float* orp = &Ored[kseg][dhg][0];
#pragma unroll
  for (int r = 0; r < 4; ++r) orp[(quad * 4 + r) * 16 + lrow] = oacc[r];
  __syncthreads();
  if (kseg == 0) {
#pragma unroll
    for (int r = 0; r < 4; ++r) {
      int idx = (quad * 4 + r) * 16 + lrow;
      float v = oacc[r] + Ored[1][dhg][idx] + Ored[2][dhg][idx] + Ored[3][dhg][idx];
      AO[(size_t)(qbase + quad * 4 + r) * 1024 + head * 64 + dhg * 16 + lrow] = (u16)f2bf(v);
    }
  }
}

// ---------------------------------------------------------------- launcher --
extern "C" void kernel_launch(void* const* d_in, const int* in_sizes, int n_in,
                              void* d_out, int out_size, void* d_ws, size_t ws_size,
                              hipStream_t stream) {
  const float* enc = (const float*)d_in[0];
  const float* mem = (const float*)d_in[1];
  const float* Wq  = (const float*)d_in[2];
  const float* bq  = (const float*)d_in[3];
  const float* Wk  = (const float*)d_in[4];
  const float* bk  = (const float*)d_in[5];
  const float* Wv  = (const float*)d_in[6];
  const float* bv  = (const float*)d_in[7];
  const float* Wo  = (const float*)d_in[8];
  const float* bo  = (const float*)d_in[9];
  const float* W1  = (const float*)d_in[10];
  const float* b1  = (const float*)d_in[11];
  const float* W2  = (const float*)d_in[12];
  const float* b2  = (const float*)d_in[13];

  char* ws = (char*)d_ws;
  const size_t MB = 1024 * 1024;
  u16* enc_bf = (u16*)(ws + 0 * MB);   // 2048x1024 bf16
  u16* mem_bf = (u16*)(ws + 4 * MB);   // 4096x1024 bf16
  u16* Wq_bf  = (u16*)(ws + 12 * MB);
  u16* Wk_bf  = (u16*)(ws + 14 * MB);
  u16* Wv_bf  = (u16*)(ws + 16 * MB);
  u16* Wo_bf  = (u16*)(ws + 18 * MB);
  u16* W1_bf  = (u16*)(ws + 20 * MB);  // 4096x2048
  u16* W2_bf  = (u16*)(ws + 36 * MB);  // 1024x4096 (padded from 1000)
  u16* Qb     = (u16*)(ws + 46 * MB);  // 2048x1024 f16
  u16* Kb     = (u16*)(ws + 50 * MB);  // 4096x1024 f16
  u16* Vtb    = (u16*)(ws + 58 * MB);  // 1024x4096 f16 (V^T)
  u16* AO     = (u16*)(ws + 66 * MB);  // 2048x1024 bf16
  u16* OUT    = (u16*)(ws + 70 * MB);  // 2048x1024 bf16
  u16* Hh     = (u16*)(ws + 74 * MB);  // 2048x4096 bf16

  ConvArgs ca;
  const float* srcs[8] = {enc, mem, Wq, Wk, Wv, Wo, W1, W2};
  u16* dsts[8] = {enc_bf, mem_bf, Wq_bf, Wk_bf, Wv_bf, Wo_bf, W1_bf, W2_bf};
  int sizes[8] = {2048 * 1024, 4096 * 1024, 1024 * 1024, 1024 * 1024,
                  1024 * 1024, 1024 * 1024, 4096 * 2048, 1000 * 4096};
  int start = 0;
  for (int i = 0; i < 8; ++i) {
    ca.src[i] = srcs[i]; ca.dst[i] = dsts[i];
    ca.start4[i] = start; start += sizes[i] / 4;
  }
  ca.start4[8] = start;
  convert_all<<<(start + 255) / 256, 256, 0, stream>>>(ca);
  zero_u16<<<(24 * 4096 + 255) / 256, 256, 0, stream>>>(W2_bf + 1000 * 4096, 24 * 4096);

  // Q = enc @ Wq^T + bq  (f16 out)  [2048,1024]
  gemm_nt<1, false, 2, false, 64><<<dim3(8, 32), 256, 0, stream>>>(
      enc_bf, 1024, Wq_bf, 1024, nullptr, 0, nullptr, 0, 1024, 0, bq, Qb, 1024, 1024);
  // K = mem @ Wk^T + bk  (f16 out)  [4096,1024]
  gemm_nt<1, false, 2, false, 64><<<dim3(8, 64), 256, 0, stream>>>(
      mem_bf, 1024, Wk_bf, 1024, nullptr, 0, nullptr, 0, 1024, 0, bk, Kb, 1024, 1024);
  // V^T = Wv @ mem^T + bv (row bias, f16 out)  [1024,4096]
  gemm_nt<2, false, 2, false, 64><<<dim3(32, 16), 256, 0, stream>>>(
      Wv_bf, 1024, mem_bf, 1024, nullptr, 0, nullptr, 0, 1024, 0, bv, Vtb, 4096, 4096);
  // attention + sparsemax
  attn_sparsemax<<<2048, 1024, 0, stream>>>((const f16*)Qb, (const f16*)Kb, (const f16*)Vtb, AO);
  // OUT = AO @ Wo^T + bo (bf16 out)  [2048,1024]
  gemm_nt<1, false, 1, false, 64><<<dim3(8, 32), 256, 0, stream>>>(
      AO, 1024, Wo_bf, 1024, nullptr, 0, nullptr, 0, 1024, 0, bo, OUT, 1024, 1024);
  // H = relu(enc@W1a^T + OUT@W1b^T + b1)  [2048,4096]
  gemm_nt<1, true, 1, true, 128><<<dim3(32, 16), 256, 0, stream>>>(
      enc_bf, 1024, W1_bf, 2048, OUT, 1024, W1_bf + 1024, 2048, 1024, 1024, b1, Hh, 4096, 4096);
  // out = H @ W2^T + b2 (fp32 out, N=1000)  [2048,1000]
  gemm_nt<1, false, 0, false, 64><<<dim3(8, 32), 256, 0, stream>>>(
      Hh, 4096, W2_bf, 4096, nullptr, 0, nullptr, 0, 4096, 0, b2, d_out, 1000, 1000);
}

// Round 6
// 757.766 us; speedup vs baseline: 4.7292x; 1.0457x over previous
//
#include <hip/hip_runtime.h>
#include <stdint.h>
#include <stddef.h>

typedef unsigned short u16;
using f16    = _Float16;
using f16x2  = __attribute__((ext_vector_type(2))) _Float16;
using f16x8  = __attribute__((ext_vector_type(8))) _Float16;
using bf16x8 = __attribute__((ext_vector_type(8))) short;
using f32x4  = __attribute__((ext_vector_type(4))) float;

__device__ __forceinline__ short f2bf(float f) {
  uint32_t u = __builtin_bit_cast(uint32_t, f);
  u += 0x7FFFu + ((u >> 16) & 1u);   // RNE
  return (short)(u >> 16);
}
__device__ __forceinline__ u16 f2h(float f) {
  return __builtin_bit_cast(u16, (f16)f);
}

// async global->LDS, 16B per lane; LDS dest must be wave-contiguous (m97/m104)
typedef const __attribute__((address_space(1))) void* gas_t;
typedef __attribute__((address_space(3))) void* las_t;
__device__ __forceinline__ void async16(const void* g, void* l) {
  __builtin_amdgcn_global_load_lds((gas_t)g, (las_t)l, 16, 0, 0);
}

// sum of 8 f16 lanes into fp32 acc via 4x v_dot2_f32_f16
__device__ __forceinline__ float dot8(f16x8 v, float acc) {
  union { f16x8 v8; f16x2 v2[4]; } u;
  u.v8 = v;
  const f16x2 one2 = {(f16)1, (f16)1};
  acc = __builtin_amdgcn_fdot2(u.v2[0], one2, acc, false);
  acc = __builtin_amdgcn_fdot2(u.v2[1], one2, acc, false);
  acc = __builtin_amdgcn_fdot2(u.v2[2], one2, acc, false);
  acc = __builtin_amdgcn_fdot2(u.v2[3], one2, acc, false);
  return acc;
}
// horizontal max of f16x8 -> float
__device__ __forceinline__ float hmax8(f16x8 v) {
  union { f16x8 v8; f16x2 v2[4]; } u;
  u.v8 = v;
  f16x2 a = __builtin_elementwise_max(u.v2[0], u.v2[1]);
  f16x2 b = __builtin_elementwise_max(u.v2[2], u.v2[3]);
  f16x2 c = __builtin_elementwise_max(a, b);
  return fmaxf((float)c[0], (float)c[1]);
}

// ---------------------------------------------------------------- convert ---
struct ConvArgs {
  const float* src[8];
  u16* dst[8];
  int start4[9];   // exclusive prefix in float4 units
};

__global__ __launch_bounds__(256) void convert_all(ConvArgs a) {
  int idx = blockIdx.x * 256 + threadIdx.x;
  if (idx >= a.start4[8]) return;
  int s = 0;
#pragma unroll
  for (int i = 1; i < 8; ++i) s += (idx >= a.start4[i]) ? 1 : 0;
  int off = idx - a.start4[s];
  const float4* sp = (const float4*)a.src[s];
  float4 v = sp[off];
  ushort4 o;
  o.x = (u16)f2bf(v.x); o.y = (u16)f2bf(v.y);
  o.z = (u16)f2bf(v.z); o.w = (u16)f2bf(v.w);
  *(ushort4*)(a.dst[s] + (size_t)off * 4) = o;
}

__global__ __launch_bounds__(256) void zero_u16(u16* p, int n) {
  int i = blockIdx.x * 256 + threadIdx.x;
  if (i < n) p[i] = 0;
}

// ------------------------------------------------------------------- GEMM ---
// C[M,N] = A[M,K1] @ B[N,K1]^T (+ A2@B2^T if DUAL) + bias, optional relu.
// bf16 inputs, m97 structure, global_load_lds width-16 staging.
// TM in {64,128}: tile TM x 128. M % TM == 0; N padded/guarded.
// BIAS: 0 none, 1 per-col, 2 per-row. OUTT: 0 f32, 1 bf16, 2 f16.
template<int BIAS, bool RELU, int OUTT, bool DUAL, int TM>
__global__ __launch_bounds__(256) void gemm_nt(
    const u16* __restrict__ A, int lda,
    const u16* __restrict__ B, int ldb,
    const u16* __restrict__ A2, int lda2,
    const u16* __restrict__ B2, int ldb2,
    int K1, int K2,
    const float* __restrict__ bias,
    void* __restrict__ C, int ldc, int N)
{
  constexpr int MI = (TM == 128) ? 4 : 2;   // 16-row m-frags per wave
  __shared__ u16 As[TM * 32];
  __shared__ u16 Bs[128 * 32];

  const int tid  = threadIdx.x;
  const int m0   = blockIdx.y * TM;
  const int n0   = blockIdx.x * 128;
  const int wave = tid >> 6, lane = tid & 63;
  const int lrow = lane & 15, quad = lane >> 4;
  const int wm   = (TM == 128) ? (wave & 1) * 64 : (wave >> 1) * 32;
  const int wn   = (TM == 128) ? (wave >> 1) * 64 : (wave & 1) * 64;

  f32x4 zero = {0.f, 0.f, 0.f, 0.f};
  f32x4 acc[MI][4];
#pragma unroll
  for (int i = 0; i < MI; ++i)
#pragma unroll
    for (int j = 0; j < 4; ++j) acc[i][j] = zero;

  const int KK = DUAL ? (K1 + K2) : K1;
  for (int k0 = 0; k0 < KK; k0 += 32) {
    const u16* Ap; const u16* Bp; int la, lb, kk;
    if (!DUAL || k0 < K1) { Ap = A;  Bp = B;  la = lda;  lb = ldb;  kk = k0; }
    else                  { Ap = A2; Bp = B2; la = lda2; lb = ldb2; kk = k0 - K1; }

#pragma unroll
    for (int i = 0; i < TM / 64; ++i) {       // A: TM*4 chunks of 16B
      int idx = i * 256 + tid;
      int row = idx >> 2, c8 = (idx & 3) * 8;
      async16(Ap + (size_t)(m0 + row) * la + kk + c8, &As[idx * 8]);
    }
#pragma unroll
    for (int i = 0; i < 2; ++i) {             // B: 512 chunks of 16B
      int idx = i * 256 + tid;
      int row = idx >> 2, c8 = (idx & 3) * 8;
      async16(Bp + (size_t)(n0 + row) * lb + kk + c8, &Bs[idx * 8]);
    }
    __syncthreads();

    bf16x8 af[MI], bfr[4];
#pragma unroll
    for (int i = 0; i < MI; ++i)
      af[i] = *(const bf16x8*)(&As[(wm + i * 16 + lrow) * 32 + quad * 8]);
#pragma unroll
    for (int j = 0; j < 4; ++j)
      bfr[j] = *(const bf16x8*)(&Bs[(wn + j * 16 + lrow) * 32 + quad * 8]);
#pragma unroll
    for (int i = 0; i < MI; ++i)
#pragma unroll
      for (int j = 0; j < 4; ++j)
        acc[i][j] = __builtin_amdgcn_mfma_f32_16x16x32_bf16(af[i], bfr[j], acc[i][j], 0, 0, 0);
    __syncthreads();
  }

  // epilogue: C layout col=lane&15, row=quad*4+r
#pragma unroll
  for (int i = 0; i < MI; ++i) {
#pragma unroll
    for (int j = 0; j < 4; ++j) {
      int gn = n0 + wn + j * 16 + lrow;
      if (gn >= N) continue;
      float bc = (BIAS == 1) ? bias[gn] : 0.0f;
#pragma unroll
      for (int r = 0; r < 4; ++r) {
        int gm = m0 + wm + i * 16 + quad * 4 + r;
        float v = acc[i][j][r] + bc;
        if (BIAS == 2) v += bias[gm];
        if (RELU) v = fmaxf(v, 0.0f);
        if (OUTT == 1)      ((u16*)C)[(size_t)gm * ldc + gn] = (u16)f2bf(v);
        else if (OUTT == 2) ((u16*)C)[(size_t)gm * ldc + gn] = f2h(v);
        else                ((float*)C)[(size_t)gm * ldc + gn] = v;
      }
    }
  }
}

// ------------------------------------------------- fused attention+sparsemax
// One block per (head, 16-query tile). 1024 threads = 16 waves.
// tau solve: 1 sum/max round + 2 five-point multisection rounds + regula
// falsi + <=3 Newton polish rounds (vs ~10-14 plain Newton rounds).
__global__ __launch_bounds__(1024) void attn_sparsemax(
    const f16* __restrict__ Q,    // [2048][1024] f16
    const f16* __restrict__ Km,   // [4096][1024] f16
    const f16* __restrict__ Vt,   // [1024][4096] f16 (V transposed)
    u16* __restrict__ AO)         // [2048][1024] bf16
{
  constexpr int SROW = 4096 + 8;          // +8 pad
  __shared__ f16 S[16 * SROW];            // 131,328 B
  __shared__ float Ored[4][4][256];       // 4 ksegs x 4 dhg x 16x16 tile, 16 KB

  const int id    = blockIdx.x;
  const int head  = (id & 7) * 2 + ((id >> 3) >> 7);  // 2 heads/XCD
  const int qblk  = (id >> 3) & 127;
  const int qbase = qblk * 16;
  const int tid   = threadIdx.x;
  const int wave  = tid >> 6, lane = tid & 63;
  const int lrow  = lane & 15, quad = lane >> 4;

  // Q fragments (A-operand: m=lane&15, k=quad*8+j)
  const f16* qp = Q + (size_t)(qbase + lrow) * 1024 + head * 64 + quad * 8;
  f16x8 qf0 = *(const f16x8*)qp;
  f16x8 qf1 = *(const f16x8*)(qp + 32);

  // ---- phase A: scores; wave w owns keys [w*256, w*256+256) -----------------
  const float scale = 1.0f / 32.0f;
#pragma unroll 2
  for (int kt = 0; kt < 16; ++kt) {
    int key0 = wave * 256 + kt * 16;
    const f16* kp = Km + (size_t)(key0 + lrow) * 1024 + head * 64 + quad * 8;
    f16x8 kf0 = *(const f16x8*)kp;
    f16x8 kf1 = *(const f16x8*)(kp + 32);
    f32x4 sc = {0.f, 0.f, 0.f, 0.f};
    sc = __builtin_amdgcn_mfma_f32_16x16x32_f16(qf0, kf0, sc, 0, 0, 0);
    sc = __builtin_amdgcn_mfma_f32_16x16x32_f16(qf1, kf1, sc, 0, 0, 0);
#pragma unroll
    for (int r = 0; r < 4; ++r)
      S[(quad * 4 + r) * SROW + key0 + lrow] = (f16)(sc[r] * scale);
  }
  __syncthreads();

  // ---- phase B: tau solve; wave w owns row w --------------------------------
  const f16 bg = (f16)65504.0f;
  const f16x8 big8  = {bg, bg, bg, bg, bg, bg, bg, bg};
  const f16x8 one8  = {(f16)1, (f16)1, (f16)1, (f16)1, (f16)1, (f16)1, (f16)1, (f16)1};
  const f16x8 zero8 = {(f16)0, (f16)0, (f16)0, (f16)0, (f16)0, (f16)0, (f16)0, (f16)0};

  {
    const int row = wave;
    f16x8 z[8];
    float sA = 0.f, sB = 0.f;
#pragma unroll
    for (int t = 0; t < 8; t += 2) {
      z[t]     = *(const f16x8*)(&S[row * SROW + t * 512 + lane * 8]);
      z[t + 1] = *(const f16x8*)(&S[row * SROW + (t + 1) * 512 + lane * 8]);
      sA = dot8(z[t], sA);
      sB = dot8(z[t + 1], sB);
    }
    f16x8 mx = z[0];
#pragma unroll
    for (int t = 1; t < 8; ++t) mx = __builtin_elementwise_max(mx, z[t]);

    // fused wave-reduce: sum + max in one 6-step shuffle ladder
    float s = sA + sB;
    float m = hmax8(mx);
#pragma unroll
    for (int o = 32; o; o >>= 1) {
      s += __shfl_xor(s, o, 64);
      m = fmaxf(m, __shfl_xor(m, o, 64));
    }

    // bracket: g(a) >= 1 (a = mean-based lower bound), g(b) = 0 (b = rowmax)
    float a = (s - 1.0f) * (1.0f / 4096.0f);
    float b = m;
    float ga = 2.0f, gb = 0.0f;   // sentinels; refined by multisection

    // two 5-point multisection rounds: bracket width /36
#pragma unroll 1
    for (int rnd = 0; rnd < 2; ++rnd) {
      float w = (b - a) * (1.0f / 6.0f);
      float tc[5], gs[5];
      f16x8 th[5];
#pragma unroll
      for (int i = 0; i < 5; ++i) {
        tc[i] = a + w * (float)(i + 1);
        f16 tq = (f16)tc[i];
        th[i] = (f16x8){tq, tq, tq, tq, tq, tq, tq, tq};
        gs[i] = 0.f;
      }
#pragma unroll
      for (int t = 0; t < 8; ++t) {
#pragma unroll
        for (int i = 0; i < 5; ++i)
          gs[i] = dot8(__builtin_elementwise_max(z[t] - th[i], zero8), gs[i]);
      }
#pragma unroll
      for (int o = 32; o; o >>= 1) {
#pragma unroll
        for (int i = 0; i < 5; ++i) gs[i] += __shfl_xor(gs[i], o, 64);
      }
#pragma unroll
      for (int i = 0; i < 5; ++i)
        if (gs[i] >= 1.0f) { a = tc[i]; ga = gs[i]; }
#pragma unroll
      for (int i = 4; i >= 0; --i)
        if (gs[i] < 1.0f) { b = tc[i]; gb = gs[i]; }
    }

    // regula falsi inside the narrow bracket (ga >= 1 > gb always)
    float tau = a + (ga - 1.0f) * (b - a) / (ga - gb);

    // Newton polish (exact once support set is stable)
#pragma unroll 1
    for (int it = 0; it < 3; ++it) {
      f16 tq = (f16)tau;
      f16x8 t8 = {tq, tq, tq, tq, tq, tq, tq, tq};
      float lsA = 0.f, lsB = 0.f, lcA = 0.f, lcB = 0.f;
#pragma unroll
      for (int t = 0; t < 8; t += 2) {
        f16x8 ma = __builtin_elementwise_max(z[t] - t8, zero8);
        f16x8 mb = __builtin_elementwise_max(z[t + 1] - t8, zero8);
        lsA = dot8(ma, lsA);
        lsB = dot8(mb, lsB);
        lcA = dot8(__builtin_elementwise_min(ma * big8, one8), lcA);
        lcB = dot8(__builtin_elementwise_min(mb * big8, one8), lcB);
      }
      float ls = lsA + lsB, lc = lcA + lcB;
#pragma unroll
      for (int o = 32; o; o >>= 1) {
        ls += __shfl_xor(ls, o, 64);
        lc += __shfl_xor(lc, o, 64);
      }
      if (lc < 0.5f) break;
      float nt = tau + (ls - 1.0f) / lc;
      if (nt == tau) break;
      tau = nt;
    }

    // write P = max(z - tau, 0) back to S
    f16 tq = (f16)tau;
    f16x8 t8 = {tq, tq, tq, tq, tq, tq, tq, tq};
#pragma unroll
    for (int t = 0; t < 8; ++t)
      *(f16x8*)(&S[row * SROW + t * 512 + lane * 8]) =
          __builtin_elementwise_max(z[t] - t8, zero8);
  }
  __syncthreads();

  // ---- phase C: O = P @ V; wave = (dhg, kseg), kseg covers 1024 keys --------
  const int dhg = wave & 3, kseg = wave >> 2;
  f32x4 oacc = {0.f, 0.f, 0.f, 0.f};
  const f16* vrow = Vt + (size_t)(head * 64 + dhg * 16 + lrow) * 4096 + kseg * 1024 + quad * 8;
  const f16* prow = &S[lrow * SROW + kseg * 1024 + quad * 8];
#pragma unroll 4
  for (int kt = 0; kt < 32; ++kt) {
    f16x8 pf = *(const f16x8*)(prow + kt * 32);
    f16x8 vf = *(const f16x8*)(vrow + kt * 32);
    oacc = __builtin_amdgcn_mfma_f32_16x16x32_f16(pf, vf, oacc, 0, 0, 0);
  }
  float* orp = &Ored[kseg][dhg][0];
#pragma unroll
  for (int r = 0; r < 4; ++r) orp[(quad * 4 + r) * 16 + lrow] = oacc[r];
  __syncthreads();
  if (kseg == 0) {
#pragma unroll
    for (int r = 0; r < 4; ++r) {
      int idx = (quad * 4 + r) * 16 + lrow;
      float v = oacc[r] + Ored[1][dhg][idx] + Ored[2][dhg][idx] + Ored[3][dhg][idx];
      AO[(size_t)(qbase + quad * 4 + r) * 1024 + head * 64 + dhg * 16 + lrow] = (u16)f2bf(v);
    }
  }
}

// ---------------------------------------------------------------- launcher --
extern "C" void kernel_launch(void* const* d_in, const int* in_sizes, int n_in,
                              void* d_out, int out_size, void* d_ws, size_t ws_size,
                              hipStream_t stream) {
  const float* enc = (const float*)d_in[0];
  const float* mem = (const float*)d_in[1];
  const float* Wq  = (const float*)d_in[2];
  const float* bq  = (const float*)d_in[3];
  const float* Wk  = (const float*)d_in[4];
  const float* bk  = (const float*)d_in[5];
  const float* Wv  = (const float*)d_in[6];
  const float* bv  = (const float*)d_in[7];
  const float* Wo  = (const float*)d_in[8];
  const float* bo  = (const float*)d_in[9];
  const float* W1  = (const float*)d_in[10];
  const float* b1  = (const float*)d_in[11];
  const float* W2  = (const float*)d_in[12];
  const float* b2  = (const float*)d_in[13];

  char* ws = (char*)d_ws;
  const size_t MB = 1024 * 1024;
  u16* enc_bf = (u16*)(ws + 0 * MB);   // 2048x1024 bf16
  u16* mem_bf = (u16*)(ws + 4 * MB);   // 4096x1024 bf16
  u16* Wq_bf  = (u16*)(ws + 12 * MB);
  u16* Wk_bf  = (u16*)(ws + 14 * MB);
  u16* Wv_bf  = (u16*)(ws + 16 * MB);
  u16* Wo_bf  = (u16*)(ws + 18 * MB);
  u16* W1_bf  = (u16*)(ws + 20 * MB);  // 4096x2048
  u16* W2_bf  = (u16*)(ws + 36 * MB);  // 1024x4096 (padded from 1000)
  u16* Qb     = (u16*)(ws + 46 * MB);  // 2048x1024 f16
  u16* Kb     = (u16*)(ws + 50 * MB);  // 4096x1024 f16
  u16* Vtb    = (u16*)(ws + 58 * MB);  // 1024x4096 f16 (V^T)
  u16* AO     = (u16*)(ws + 66 * MB);  // 2048x1024 bf16
  u16* OUT    = (u16*)(ws + 70 * MB);  // 2048x1024 bf16
  u16* Hh     = (u16*)(ws + 74 * MB);  // 2048x4096 bf16

  ConvArgs ca;
  const float* srcs[8] = {enc, mem, Wq, Wk, Wv, Wo, W1, W2};
  u16* dsts[8] = {enc_bf, mem_bf, Wq_bf, Wk_bf, Wv_bf, Wo_bf, W1_bf, W2_bf};
  int sizes[8] = {2048 * 1024, 4096 * 1024, 1024 * 1024, 1024 * 1024,
                  1024 * 1024, 1024 * 1024, 4096 * 2048, 1000 * 4096};
  int start = 0;
  for (int i = 0; i < 8; ++i) {
    ca.src[i] = srcs[i]; ca.dst[i] = dsts[i];
    ca.start4[i] = start; start += sizes[i] / 4;
  }
  ca.start4[8] = start;
  convert_all<<<(start + 255) / 256, 256, 0, stream>>>(ca);
  zero_u16<<<(24 * 4096 + 255) / 256, 256, 0, stream>>>(W2_bf + 1000 * 4096, 24 * 4096);

  // Q = enc @ Wq^T + bq  (f16 out)  [2048,1024]
  gemm_nt<1, false, 2, false, 64><<<dim3(8, 32), 256, 0, stream>>>(
      enc_bf, 1024, Wq_bf, 1024, nullptr, 0, nullptr, 0, 1024, 0, bq, Qb, 1024, 1024);
  // K = mem @ Wk^T + bk  (f16 out)  [4096,1024]
  gemm_nt<1, false, 2, false, 64><<<dim3(8, 64), 256, 0, stream>>>(
      mem_bf, 1024, Wk_bf, 1024, nullptr, 0, nullptr, 0, 1024, 0, bk, Kb, 1024, 1024);
  // V^T = Wv @ mem^T + bv (row bias, f16 out)  [1024,4096]
  gemm_nt<2, false, 2, false, 64><<<dim3(32, 16), 256, 0, stream>>>(
      Wv_bf, 1024, mem_bf, 1024, nullptr, 0, nullptr, 0, 1024, 0, bv, Vtb, 4096, 4096);
  // attention + sparsemax
  attn_sparsemax<<<2048, 1024, 0, stream>>>((const f16*)Qb, (const f16*)Kb, (const f16*)Vtb, AO);
  // OUT = AO @ Wo^T + bo (bf16 out)  [2048,1024]
  gemm_nt<1, false, 1, false, 64><<<dim3(8, 32), 256, 0, stream>>>(
      AO, 1024, Wo_bf, 1024, nullptr, 0, nullptr, 0, 1024, 0, bo, OUT, 1024, 1024);
  // H = relu(enc@W1a^T + OUT@W1b^T + b1)  [2048,4096]
  gemm_nt<1, true, 1, true, 128><<<dim3(32, 16), 256, 0, stream>>>(
      enc_bf, 1024, W1_bf, 2048, OUT, 1024, W1_bf + 1024, 2048, 1024, 1024, b1, Hh, 4096, 4096);
  // out = H @ W2^T + b2 (fp32 out, N=1000)  [2048,1000]
  gemm_nt<1, false, 0, false, 64><<<dim3(8, 32), 256, 0, stream>>>(
      Hh, 4096, W2_bf, 4096, nullptr, 0, nullptr, 0, 4096, 0, b2, d_out, 1000, 1000);
}

// Round 7
// 756.249 us; speedup vs baseline: 4.7387x; 1.0020x over previous
//
#include <hip/hip_runtime.h>
#include <stdint.h>
#include <stddef.h>

typedef unsigned short u16;
using f16    = _Float16;
using f16x2  = __attribute__((ext_vector_type(2))) _Float16;
using f16x8  = __attribute__((ext_vector_type(8))) _Float16;
using bf16x8 = __attribute__((ext_vector_type(8))) short;
using f32x4  = __attribute__((ext_vector_type(4))) float;

__device__ __forceinline__ short f2bf(float f) {
  uint32_t u = __builtin_bit_cast(uint32_t, f);
  u += 0x7FFFu + ((u >> 16) & 1u);   // RNE
  return (short)(u >> 16);
}
__device__ __forceinline__ u16 f2h(float f) {
  return __builtin_bit_cast(u16, (f16)f);
}

// async global->LDS, 16B per lane; LDS dest must be wave-contiguous (m97/m104)
typedef const __attribute__((address_space(1))) void* gas_t;
typedef __attribute__((address_space(3))) void* las_t;
__device__ __forceinline__ void async16(const void* g, void* l) {
  __builtin_amdgcn_global_load_lds((gas_t)g, (las_t)l, 16, 0, 0);
}

// sum of 8 f16 lanes into fp32 acc via 4x v_dot2_f32_f16
__device__ __forceinline__ float dot8(f16x8 v, float acc) {
  union { f16x8 v8; f16x2 v2[4]; } u;
  u.v8 = v;
  const f16x2 one2 = {(f16)1, (f16)1};
  acc = __builtin_amdgcn_fdot2(u.v2[0], one2, acc, false);
  acc = __builtin_amdgcn_fdot2(u.v2[1], one2, acc, false);
  acc = __builtin_amdgcn_fdot2(u.v2[2], one2, acc, false);
  acc = __builtin_amdgcn_fdot2(u.v2[3], one2, acc, false);
  return acc;
}
// horizontal max of f16x8 -> float
__device__ __forceinline__ float hmax8(f16x8 v) {
  union { f16x8 v8; f16x2 v2[4]; } u;
  u.v8 = v;
  f16x2 a = __builtin_elementwise_max(u.v2[0], u.v2[1]);
  f16x2 b = __builtin_elementwise_max(u.v2[2], u.v2[3]);
  f16x2 c = __builtin_elementwise_max(a, b);
  return fmaxf((float)c[0], (float)c[1]);
}

// ---- shared sparsemax row solver: z[8] register-resident, returns tau ------
__device__ __forceinline__ float solve_tau(const f16x8* z) {
  const f16 bg = (f16)65504.0f;
  const f16x8 big8  = {bg, bg, bg, bg, bg, bg, bg, bg};
  const f16x8 one8  = {(f16)1, (f16)1, (f16)1, (f16)1, (f16)1, (f16)1, (f16)1, (f16)1};
  const f16x8 zero8 = {(f16)0, (f16)0, (f16)0, (f16)0, (f16)0, (f16)0, (f16)0, (f16)0};

  float sA = 0.f, sB = 0.f;
  f16x8 mx = z[0];
#pragma unroll
  for (int t = 0; t < 8; t += 2) {
    sA = dot8(z[t], sA);
    sB = dot8(z[t + 1], sB);
  }
#pragma unroll
  for (int t = 1; t < 8; ++t) mx = __builtin_elementwise_max(mx, z[t]);

  float s = sA + sB;
  float m = hmax8(mx);
#pragma unroll
  for (int o = 32; o; o >>= 1) {
    s += __shfl_xor(s, o, 64);
    m = fmaxf(m, __shfl_xor(m, o, 64));
  }

  float a = (s - 1.0f) * (1.0f / 4096.0f);
  float b = m;
  float ga = 2.0f, gb = 0.0f;

#pragma unroll 1
  for (int rnd = 0; rnd < 2; ++rnd) {
    float w = (b - a) * (1.0f / 6.0f);
    float tc[5], gs[5];
    f16x8 th[5];
#pragma unroll
    for (int i = 0; i < 5; ++i) {
      tc[i] = a + w * (float)(i + 1);
      f16 tq = (f16)tc[i];
      th[i] = (f16x8){tq, tq, tq, tq, tq, tq, tq, tq};
      gs[i] = 0.f;
    }
#pragma unroll
    for (int t = 0; t < 8; ++t) {
#pragma unroll
      for (int i = 0; i < 5; ++i)
        gs[i] = dot8(__builtin_elementwise_max(z[t] - th[i], zero8), gs[i]);
    }
#pragma unroll
    for (int o = 32; o; o >>= 1) {
#pragma unroll
      for (int i = 0; i < 5; ++i) gs[i] += __shfl_xor(gs[i], o, 64);
    }
#pragma unroll
    for (int i = 0; i < 5; ++i)
      if (gs[i] >= 1.0f) { a = tc[i]; ga = gs[i]; }
#pragma unroll
    for (int i = 4; i >= 0; --i)
      if (gs[i] < 1.0f) { b = tc[i]; gb = gs[i]; }
  }

  float tau = a + (ga - 1.0f) * (b - a) / (ga - gb);

#pragma unroll 1
  for (int it = 0; it < 3; ++it) {
    f16 tq = (f16)tau;
    f16x8 t8 = {tq, tq, tq, tq, tq, tq, tq, tq};
    float lsA = 0.f, lsB = 0.f, lcA = 0.f, lcB = 0.f;
#pragma unroll
    for (int t = 0; t < 8; t += 2) {
      f16x8 ma = __builtin_elementwise_max(z[t] - t8, zero8);
      f16x8 mb = __builtin_elementwise_max(z[t + 1] - t8, zero8);
      lsA = dot8(ma, lsA);
      lsB = dot8(mb, lsB);
      lcA = dot8(__builtin_elementwise_min(ma * big8, one8), lcA);
      lcB = dot8(__builtin_elementwise_min(mb * big8, one8), lcB);
    }
    float ls = lsA + lsB, lc = lcA + lcB;
#pragma unroll
    for (int o = 32; o; o >>= 1) {
      ls += __shfl_xor(ls, o, 64);
      lc += __shfl_xor(lc, o, 64);
    }
    if (lc < 0.5f) break;
    float nt = tau + (ls - 1.0f) / lc;
    if (nt == tau) break;
    tau = nt;
  }
  return tau;
}

// ---------------------------------------------------------------- convert ---
struct ConvArgs {
  const float* src[8];
  u16* dst[8];
  int start4[9];   // exclusive prefix in float4 units
};

__global__ __launch_bounds__(256) void convert_all(ConvArgs a) {
  int idx = blockIdx.x * 256 + threadIdx.x;
  if (idx >= a.start4[8]) return;
  int s = 0;
#pragma unroll
  for (int i = 1; i < 8; ++i) s += (idx >= a.start4[i]) ? 1 : 0;
  int off = idx - a.start4[s];
  const float4* sp = (const float4*)a.src[s];
  float4 v = sp[off];
  ushort4 o;
  o.x = (u16)f2bf(v.x); o.y = (u16)f2bf(v.y);
  o.z = (u16)f2bf(v.z); o.w = (u16)f2bf(v.w);
  *(ushort4*)(a.dst[s] + (size_t)off * 4) = o;
}

__global__ __launch_bounds__(256) void zero_u16(u16* p, int n) {
  int i = blockIdx.x * 256 + threadIdx.x;
  if (i < n) p[i] = 0;
}

// ------------------------------------------------------------------- GEMM ---
// C[M,N] = A[M,K1] @ B[N,K1]^T (+ A2@B2^T if DUAL) + bias, then *escale,
// optional relu. m97 structure, global_load_lds width-16 staging.
// TM in {64,128}. BIAS: 0 none, 1 per-col, 2 per-row.
// OUTT: 0 f32, 1 bf16, 2 f16. IN: 0 bf16, 1 f16.
// Batched via blockIdx.z with element strides bzA/bzB/bzC.
template<int BIAS, bool RELU, int OUTT, bool DUAL, int TM, int IN>
__global__ __launch_bounds__(256) void gemm_nt(
    const u16* __restrict__ A, int lda,
    const u16* __restrict__ B, int ldb,
    const u16* __restrict__ A2, int lda2,
    const u16* __restrict__ B2, int ldb2,
    int K1, int K2,
    const float* __restrict__ bias,
    void* __restrict__ C, int ldc, int N,
    float escale, size_t bzA, size_t bzB, size_t bzC)
{
  constexpr int MI = (TM == 128) ? 4 : 2;   // 16-row m-frags per wave
  __shared__ u16 As[TM * 32];
  __shared__ u16 Bs[128 * 32];

  const size_t zo = (size_t)blockIdx.z;
  A += zo * bzA;
  B += zo * bzB;
  u16*   C16 = (u16*)C + zo * bzC;
  float* C32 = (float*)C + zo * bzC;

  const int tid  = threadIdx.x;
  const int m0   = blockIdx.y * TM;
  const int n0   = blockIdx.x * 128;
  const int wave = tid >> 6, lane = tid & 63;
  const int lrow = lane & 15, quad = lane >> 4;
  const int wm   = (TM == 128) ? (wave & 1) * 64 : (wave >> 1) * 32;
  const int wn   = (TM == 128) ? (wave >> 1) * 64 : (wave & 1) * 64;

  f32x4 zero = {0.f, 0.f, 0.f, 0.f};
  f32x4 acc[MI][4];
#pragma unroll
  for (int i = 0; i < MI; ++i)
#pragma unroll
    for (int j = 0; j < 4; ++j) acc[i][j] = zero;

  const int KK = DUAL ? (K1 + K2) : K1;
  for (int k0 = 0; k0 < KK; k0 += 32) {
    const u16* Ap; const u16* Bp; int la, lb, kk;
    if (!DUAL || k0 < K1) { Ap = A;  Bp = B;  la = lda;  lb = ldb;  kk = k0; }
    else                  { Ap = A2; Bp = B2; la = lda2; lb = ldb2; kk = k0 - K1; }

#pragma unroll
    for (int i = 0; i < TM / 64; ++i) {       // A: TM*4 chunks of 16B
      int idx = i * 256 + tid;
      int row = idx >> 2, c8 = (idx & 3) * 8;
      async16(Ap + (size_t)(m0 + row) * la + kk + c8, &As[idx * 8]);
    }
#pragma unroll
    for (int i = 0; i < 2; ++i) {             // B: 512 chunks of 16B
      int idx = i * 256 + tid;
      int row = idx >> 2, c8 = (idx & 3) * 8;
      async16(Bp + (size_t)(n0 + row) * lb + kk + c8, &Bs[idx * 8]);
    }
    __syncthreads();

    bf16x8 af[MI], bfr[4];
#pragma unroll
    for (int i = 0; i < MI; ++i)
      af[i] = *(const bf16x8*)(&As[(wm + i * 16 + lrow) * 32 + quad * 8]);
#pragma unroll
    for (int j = 0; j < 4; ++j)
      bfr[j] = *(const bf16x8*)(&Bs[(wn + j * 16 + lrow) * 32 + quad * 8]);
#pragma unroll
    for (int i = 0; i < MI; ++i)
#pragma unroll
      for (int j = 0; j < 4; ++j) {
        if constexpr (IN == 0)
          acc[i][j] = __builtin_amdgcn_mfma_f32_16x16x32_bf16(af[i], bfr[j], acc[i][j], 0, 0, 0);
        else
          acc[i][j] = __builtin_amdgcn_mfma_f32_16x16x32_f16(
              __builtin_bit_cast(f16x8, af[i]), __builtin_bit_cast(f16x8, bfr[j]),
              acc[i][j], 0, 0, 0);
      }
    __syncthreads();
  }

  // epilogue: C layout col=lane&15, row=quad*4+r
#pragma unroll
  for (int i = 0; i < MI; ++i) {
#pragma unroll
    for (int j = 0; j < 4; ++j) {
      int gn = n0 + wn + j * 16 + lrow;
      if (gn >= N) continue;
      float bc = (BIAS == 1) ? bias[gn] : 0.0f;
#pragma unroll
      for (int r = 0; r < 4; ++r) {
        int gm = m0 + wm + i * 16 + quad * 4 + r;
        float v = acc[i][j][r] + bc;
        if (BIAS == 2) v += bias[gm];
        v *= escale;
        if (RELU) v = fmaxf(v, 0.0f);
        if (OUTT == 1)      C16[(size_t)gm * ldc + gn] = (u16)f2bf(v);
        else if (OUTT == 2) C16[(size_t)gm * ldc + gn] = f2h(v);
        else                C32[(size_t)gm * ldc + gn] = v;
      }
    }
  }
}

// ------------------------------------------------- standalone sparsemax -----
// One wave per row (2 rows/wave serial); row register-resident; no barriers.
// In-place: S row -> P row. 4096 blocks x 256 threads, 32768 rows.
__global__ __launch_bounds__(256) void sparsemax_rows(u16* __restrict__ Sp) {
  const int wave = threadIdx.x >> 6, lane = threadIdx.x & 63;
  const int wid  = blockIdx.x * 4 + wave;
  const f16x8 zero8 = {(f16)0, (f16)0, (f16)0, (f16)0, (f16)0, (f16)0, (f16)0, (f16)0};

#pragma unroll 1
  for (int rr = 0; rr < 2; ++rr) {
    const size_t row = (size_t)wid * 2 + rr;
    f16* Srow = (f16*)Sp + row * 4096;
    f16x8 z[8];
#pragma unroll
    for (int t = 0; t < 8; ++t)
      z[t] = *(const f16x8*)(Srow + t * 512 + lane * 8);

    float tau = solve_tau(z);

    f16 tq = (f16)tau;
    f16x8 t8 = {tq, tq, tq, tq, tq, tq, tq, tq};
#pragma unroll
    for (int t = 0; t < 8; ++t)
      *(f16x8*)(Srow + t * 512 + lane * 8) =
          __builtin_elementwise_max(z[t] - t8, zero8);
  }
}

// ------------------------------------------------- fused attention (fallback)
// Used only when ws_size is too small for the split path. Identical to R6
// except scale is a parameter (Qb is now pre-scaled by 1/32).
__global__ __launch_bounds__(1024) void attn_sparsemax(
    const f16* __restrict__ Q,    // [2048][1024] f16 (pre-scaled)
    const f16* __restrict__ Km,   // [4096][1024] f16
    const f16* __restrict__ Vt,   // [1024][4096] f16 (V transposed)
    u16* __restrict__ AO)         // [2048][1024] bf16
{
  constexpr int SROW = 4096 + 8;
  __shared__ f16 S[16 * SROW];
  __shared__ float Ored[4][4][256];

  const int id    = blockIdx.x;
  const int head  = (id & 7) * 2 + ((id >> 3) >> 7);
  const int qblk  = (id >> 3) & 127;
  const int qbase = qblk * 16;
  const int tid   = threadIdx.x;
  const int wave  = tid >> 6, lane = tid & 63;
  const int lrow  = lane & 15, quad = lane >> 4;

  const f16* qp = Q + (size_t)(qbase + lrow) * 1024 + head * 64 + quad * 8;
  f16x8 qf0 = *(const f16x8*)qp;
  f16x8 qf1 = *(const f16x8*)(qp + 32);

#pragma unroll 2
  for (int kt = 0; kt < 16; ++kt) {
    int key0 = wave * 256 + kt * 16;
    const f16* kp = Km + (size_t)(key0 + lrow) * 1024 + head * 64 + quad * 8;
    f16x8 kf0 = *(const f16x8*)kp;
    f16x8 kf1 = *(const f16x8*)(kp + 32);
    f32x4 sc = {0.f, 0.f, 0.f, 0.f};
    sc = __builtin_amdgcn_mfma_f32_16x16x32_f16(qf0, kf0, sc, 0, 0, 0);
    sc = __builtin_amdgcn_mfma_f32_16x16x32_f16(qf1, kf1, sc, 0, 0, 0);
#pragma unroll
    for (int r = 0; r < 4; ++r)
      S[(quad * 4 + r) * SROW + key0 + lrow] = (f16)sc[r];
  }
  __syncthreads();

  {
    const int row = wave;
    const f16x8 zero8 = {(f16)0, (f16)0, (f16)0, (f16)0, (f16)0, (f16)0, (f16)0, (f16)0};
    f16x8 z[8];
#pragma unroll
    for (int t = 0; t < 8; ++t)
      z[t] = *(const f16x8*)(&S[row * SROW + t * 512 + lane * 8]);
    float tau = solve_tau(z);
    f16 tq = (f16)tau;
    f16x8 t8 = {tq, tq, tq, tq, tq, tq, tq, tq};
#pragma unroll
    for (int t = 0; t < 8; ++t)
      *(f16x8*)(&S[row * SROW + t * 512 + lane * 8]) =
          __builtin_elementwise_max(z[t] - t8, zero8);
  }
  __syncthreads();

  const int dhg = wave & 3, kseg = wave >> 2;
  f32x4 oacc = {0.f, 0.f, 0.f, 0.f};
  const f16* vrow = Vt + (size_t)(head * 64 + dhg * 16 + lrow) * 4096 + kseg * 1024 + quad * 8;
  const f16* prow = &S[lrow * SROW + kseg * 1024 + quad * 8];
#pragma unroll 4
  for (int kt = 0; kt < 32; ++kt) {
    f16x8 pf = *(const f16x8*)(prow + kt * 32);
    f16x8 vf = *(const f16x8*)(vrow + kt * 32);
    oacc = __builtin_amdgcn_mfma_f32_16x16x32_f16(pf, vf, oacc, 0, 0, 0);
  }
  float* orp = &Ored[kseg][dhg][0];
#pragma unroll
  for (int r = 0; r < 4; ++r) orp[(quad * 4 + r) * 16 + lrow] = oacc[r];
  __syncthreads();
  if (kseg == 0) {
#pragma unroll
    for (int r = 0; r < 4; ++r) {
      int idx = (quad * 4 + r) * 16 + lrow;
      float v = oacc[r] + Ored[1][dhg][idx] + Ored[2][dhg][idx] + Ored[3][dhg][idx];
      AO[(size_t)(qbase + quad * 4 + r) * 1024 + head * 64 + dhg * 16 + lrow] = (u16)f2bf(v);
    }
  }
}

// ---------------------------------------------------------------- launcher --
extern "C" void kernel_launch(void* const* d_in, const int* in_sizes, int n_in,
                              void* d_out, int out_size, void* d_ws, size_t ws_size,
                              hipStream_t stream) {
  const float* enc = (const float*)d_in[0];
  const float* mem = (const float*)d_in[1];
  const float* Wq  = (const float*)d_in[2];
  const float* bq  = (const float*)d_in[3];
  const float* Wk  = (const float*)d_in[4];
  const float* bk  = (const float*)d_in[5];
  const float* Wv  = (const float*)d_in[6];
  const float* bv  = (const float*)d_in[7];
  const float* Wo  = (const float*)d_in[8];
  const float* bo  = (const float*)d_in[9];
  const float* W1  = (const float*)d_in[10];
  const float* b1  = (const float*)d_in[11];
  const float* W2  = (const float*)d_in[12];
  const float* b2  = (const float*)d_in[13];

  char* ws = (char*)d_ws;
  const size_t MB = 1024 * 1024;
  u16* enc_bf = (u16*)(ws + 0 * MB);   // 2048x1024 bf16
  u16* mem_bf = (u16*)(ws + 4 * MB);   // 4096x1024 bf16
  u16* Wq_bf  = (u16*)(ws + 12 * MB);
  u16* Wk_bf  = (u16*)(ws + 14 * MB);
  u16* Wv_bf  = (u16*)(ws + 16 * MB);
  u16* Wo_bf  = (u16*)(ws + 18 * MB);
  u16* W1_bf  = (u16*)(ws + 20 * MB);  // 4096x2048
  u16* W2_bf  = (u16*)(ws + 36 * MB);  // 1024x4096 (padded from 1000)
  u16* Qb     = (u16*)(ws + 46 * MB);  // 2048x1024 f16 (pre-scaled by 1/32)
  u16* Kb     = (u16*)(ws + 50 * MB);  // 4096x1024 f16
  u16* Vtb    = (u16*)(ws + 58 * MB);  // 1024x4096 f16 (V^T)
  u16* AO     = (u16*)(ws + 66 * MB);  // 2048x1024 bf16
  u16* OUT    = (u16*)(ws + 70 * MB);  // 2048x1024 bf16
  u16* Hh     = (u16*)(ws + 74 * MB);  // 2048x4096 bf16
  u16* Sbuf   = (u16*)(ws + 96 * MB);  // 16x2048x4096 f16 = 256 MB (split path)

  const bool split = ws_size >= (size_t)360 * MB;  // constant per harness

  ConvArgs ca;
  const float* srcs[8] = {enc, mem, Wq, Wk, Wv, Wo, W1, W2};
  u16* dsts[8] = {enc_bf, mem_bf, Wq_bf, Wk_bf, Wv_bf, Wo_bf, W1_bf, W2_bf};
  int sizes[8] = {2048 * 1024, 4096 * 1024, 1024 * 1024, 1024 * 1024,
                  1024 * 1024, 1024 * 1024, 4096 * 2048, 1000 * 4096};
  int start = 0;
  for (int i = 0; i < 8; ++i) {
    ca.src[i] = srcs[i]; ca.dst[i] = dsts[i];
    ca.start4[i] = start; start += sizes[i] / 4;
  }
  ca.start4[8] = start;
  convert_all<<<(start + 255) / 256, 256, 0, stream>>>(ca);
  zero_u16<<<(24 * 4096 + 255) / 256, 256, 0, stream>>>(W2_bf + 1000 * 4096, 24 * 4096);

  // Q = (enc @ Wq^T + bq) / 32   (f16 out, scale folded)
  gemm_nt<1, false, 2, false, 64, 0><<<dim3(8, 32), 256, 0, stream>>>(
      enc_bf, 1024, Wq_bf, 1024, nullptr, 0, nullptr, 0, 1024, 0, bq,
      Qb, 1024, 1024, 1.0f / 32.0f, 0, 0, 0);
  // K = mem @ Wk^T + bk  (f16 out)
  gemm_nt<1, false, 2, false, 64, 0><<<dim3(8, 64), 256, 0, stream>>>(
      mem_bf, 1024, Wk_bf, 1024, nullptr, 0, nullptr, 0, 1024, 0, bk,
      Kb, 1024, 1024, 1.0f, 0, 0, 0);
  // V^T = Wv @ mem^T + bv (row bias, f16 out)
  gemm_nt<2, false, 2, false, 64, 0><<<dim3(32, 16), 256, 0, stream>>>(
      Wv_bf, 1024, mem_bf, 1024, nullptr, 0, nullptr, 0, 1024, 0, bv,
      Vtb, 4096, 4096, 1.0f, 0, 0, 0);

  if (split) {
    // S[h] = Qhat_h @ K_h^T   [2048,4096] per head, K=64, f16 in/out
    gemm_nt<0, false, 2, false, 128, 1><<<dim3(32, 16, 16), 256, 0, stream>>>(
        Qb, 1024, Kb, 1024, nullptr, 0, nullptr, 0, 64, 0, nullptr,
        Sbuf, 4096, 4096, 1.0f, 64, 64, (size_t)2048 * 4096);
    // sparsemax in place over 32768 rows
    sparsemax_rows<<<4096, 256, 0, stream>>>(Sbuf);
    // AO[:, h*64:(h+1)*64] = P_h @ V_h  (K=4096, N=64, bf16 out)
    gemm_nt<0, false, 1, false, 64, 1><<<dim3(1, 32, 16), 256, 0, stream>>>(
        Sbuf, 4096, Vtb, 4096, nullptr, 0, nullptr, 0, 4096, 0, nullptr,
        AO, 1024, 64, 1.0f, (size_t)2048 * 4096, (size_t)64 * 4096, 64);
  } else {
    attn_sparsemax<<<2048, 1024, 0, stream>>>(
        (const f16*)Qb, (const f16*)Kb, (const f16*)Vtb, AO);
  }

  // OUT = AO @ Wo^T + bo (bf16 out)
  gemm_nt<1, false, 1, false, 64, 0><<<dim3(8, 32), 256, 0, stream>>>(
      AO, 1024, Wo_bf, 1024, nullptr, 0, nullptr, 0, 1024, 0, bo,
      OUT, 1024, 1024, 1.0f, 0, 0, 0);
  // H = relu(enc@W1a^T + OUT@W1b^T + b1)
  gemm_nt<1, true, 1, true, 128, 0><<<dim3(32, 16), 256, 0, stream>>>(
      enc_bf, 1024, W1_bf, 2048, OUT, 1024, W1_bf + 1024, 2048, 1024, 1024, b1,
      Hh, 4096, 4096, 1.0f, 0, 0, 0);
  // out = H @ W2^T + b2 (fp32 out, N=1000)
  gemm_nt<1, false, 0, false, 64, 0><<<dim3(8, 32), 256, 0, stream>>>(
      Hh, 4096, W2_bf, 4096, nullptr, 0, nullptr, 0, 4096, 0, b2,
      d_out, 1000, 1000, 1.0f, 0, 0, 0);
}